// Round 4
// baseline (817.009 us; speedup 1.0000x reference)
//
#include <hip/hip_runtime.h>
#include <math.h>

#define H 256

typedef __attribute__((ext_vector_type(8))) short short8;
typedef __attribute__((ext_vector_type(4))) float f32x4;
typedef __attribute__((ext_vector_type(4))) int int4v;
typedef __attribute__((ext_vector_type(2))) unsigned int uint2v;
typedef unsigned short ushort_t;

__device__ __forceinline__ float bf2f(unsigned short u) {
    union { unsigned int i; float f; } v; v.i = ((unsigned int)u) << 16; return v.f;
}
__device__ __forceinline__ unsigned short f2bf(float f) {
    union { float f; unsigned int i; } v; v.f = f;
    unsigned int r = v.i + 0x7FFFu + ((v.i >> 16) & 1u);   // RNE
    return (unsigned short)(r >> 16);
}
__device__ __forceinline__ void glds16(const void* g, void* l) {
    __builtin_amdgcn_global_load_lds((const __attribute__((address_space(1))) void*)g,
                                     (__attribute__((address_space(3))) void*)l, 16, 0, 0);
}
__device__ __forceinline__ int4v pack_f32x8_bf16(const float* p) {
    float4 f0 = *(const float4*)(p);
    float4 f1 = *(const float4*)(p + 4);
    int4v d;
    d.x = (int)((unsigned)f2bf(f0.x) | ((unsigned)f2bf(f0.y) << 16));
    d.y = (int)((unsigned)f2bf(f0.z) | ((unsigned)f2bf(f0.w) << 16));
    d.z = (int)((unsigned)f2bf(f1.x) | ((unsigned)f2bf(f1.y) << 16));
    d.w = (int)((unsigned)f2bf(f1.z) | ((unsigned)f2bf(f1.w) << 16));
    return d;
}

// ---------------- prep ----------------
__global__ void prep_weights(const float* __restrict__ Wm, const float* __restrict__ Wg,
                             const float* __restrict__ Wu,
                             ushort_t* __restrict__ Wmt, ushort_t* __restrict__ Wgt,
                             ushort_t* __restrict__ Wut) {
    int idx = blockIdx.x * 256 + threadIdx.x;
    if (idx < 65536) {                       // [256][256] -> [n][k]
        int n = idx >> 8, k = idx & 255;
        Wmt[idx] = f2bf(Wm[(size_t)k * 256 + n]);
        Wut[idx] = f2bf(Wu[(size_t)k * 256 + n]);
    }
    if (idx < 131072) {                      // [512][256] -> [n][512 k]
        int n = idx >> 9, k = idx & 511;
        Wgt[idx] = f2bf(Wg[(size_t)k * 256 + n]);
    }
}

__global__ void imap_init(int* __restrict__ imap, int R) {
    int r = blockIdx.x * 256 + threadIdx.x;
    if (r < R) imap[r] = -1;
}
__global__ void imap_scatter(const int* __restrict__ tgt, int* __restrict__ imap, int E) {
    int e = blockIdx.x * 256 + threadIdx.x;
    if (e < E) imap[tgt[e]] = e;
}

// ---------------- x -> bf16 copy ----------------
__global__ void conv_bf16(const float* __restrict__ x, ushort_t* __restrict__ yb, size_t n8) {
    size_t i = (size_t)blockIdx.x * blockDim.x + threadIdx.x;
    size_t stride = (size_t)gridDim.x * blockDim.x;
    for (; i < n8; i += stride)
        *(int4v*)(yb + i * 8) = pack_f32x8_bf16(x + i * 8);
}

// ---------------- segment mean: wave-per-edge, unroll-4 ----------------
__global__ __launch_bounds__(256) void seg_mean_bf16(const ushort_t* __restrict__ yb,
                                                     const int* __restrict__ ptr,
                                                     const int* __restrict__ src,
                                                     ushort_t* __restrict__ smb, int E) {
    int e = blockIdx.x * 4 + (threadIdx.x >> 6);
    if (e >= E) return;
    int lane = threadIdx.x & 63;
    int s = ptr[e], t = ptr[e + 1];
    float a0 = 0.f, a1 = 0.f, a2 = 0.f, a3 = 0.f;
    int i = s;
    for (; i + 4 <= t; i += 4) {
        uint2v v0 = *(const uint2v*)(yb + (size_t)src[i + 0] * H + lane * 4);
        uint2v v1 = *(const uint2v*)(yb + (size_t)src[i + 1] * H + lane * 4);
        uint2v v2 = *(const uint2v*)(yb + (size_t)src[i + 2] * H + lane * 4);
        uint2v v3 = *(const uint2v*)(yb + (size_t)src[i + 3] * H + lane * 4);
        a0 += bf2f(v0.x & 0xffff) + bf2f(v1.x & 0xffff) + bf2f(v2.x & 0xffff) + bf2f(v3.x & 0xffff);
        a1 += bf2f(v0.x >> 16)    + bf2f(v1.x >> 16)    + bf2f(v2.x >> 16)    + bf2f(v3.x >> 16);
        a2 += bf2f(v0.y & 0xffff) + bf2f(v1.y & 0xffff) + bf2f(v2.y & 0xffff) + bf2f(v3.y & 0xffff);
        a3 += bf2f(v0.y >> 16)    + bf2f(v1.y >> 16)    + bf2f(v2.y >> 16)    + bf2f(v3.y >> 16);
    }
    for (; i < t; ++i) {
        uint2v v = *(const uint2v*)(yb + (size_t)src[i] * H + lane * 4);
        a0 += bf2f(v.x & 0xffff); a1 += bf2f(v.x >> 16);
        a2 += bf2f(v.y & 0xffff); a3 += bf2f(v.y >> 16);
    }
    float inv = 1.f / (float)(t - s);
    uint2v o;
    o.x = (unsigned)f2bf(a0 * inv) | ((unsigned)f2bf(a1 * inv) << 16);
    o.y = (unsigned)f2bf(a2 * inv) | ((unsigned)f2bf(a3 * inv) << 16);
    *(uint2v*)(smb + (size_t)e * H + lane * 4) = o;
}

// fallback: fp32 gather (small-ws path)
__global__ __launch_bounds__(256) void seg_mean_f32w(const float* __restrict__ x,
                                                     const int* __restrict__ ptr,
                                                     const int* __restrict__ src,
                                                     ushort_t* __restrict__ smb, int E) {
    int e = blockIdx.x * 4 + (threadIdx.x >> 6);
    if (e >= E) return;
    int lane = threadIdx.x & 63;
    int s = ptr[e], t = ptr[e + 1];
    float a0 = 0.f, a1 = 0.f, a2 = 0.f, a3 = 0.f;
    int i = s;
    for (; i + 4 <= t; i += 4) {
        float4 v0 = *(const float4*)(x + (size_t)src[i + 0] * H + lane * 4);
        float4 v1 = *(const float4*)(x + (size_t)src[i + 1] * H + lane * 4);
        float4 v2 = *(const float4*)(x + (size_t)src[i + 2] * H + lane * 4);
        float4 v3 = *(const float4*)(x + (size_t)src[i + 3] * H + lane * 4);
        a0 += v0.x + v1.x + v2.x + v3.x;
        a1 += v0.y + v1.y + v2.y + v3.y;
        a2 += v0.z + v1.z + v2.z + v3.z;
        a3 += v0.w + v1.w + v2.w + v3.w;
    }
    for (; i < t; ++i) {
        float4 v = *(const float4*)(x + (size_t)src[i] * H + lane * 4);
        a0 += v.x; a1 += v.y; a2 += v.z; a3 += v.w;
    }
    float inv = 1.f / (float)(t - s);
    uint2v o;
    o.x = (unsigned)f2bf(a0 * inv) | ((unsigned)f2bf(a1 * inv) << 16);
    o.y = (unsigned)f2bf(a2 * inv) | ((unsigned)f2bf(a3 * inv) << 16);
    *(uint2v*)(smb + (size_t)e * H + lane * 4) = o;
}

// ---------------- W-resident streaming MFMA GEMM ----------------
// C[M,NCOLS@c0] = A[M,KTOT] @ W[KTOT, c0:c0+NCOLS] (+epilogue).
// W (col-block) lives entirely in LDS (128 KiB), XOR-swizzled chunk^= (n&7)
// -> 2-way (free) conflicts on B-fragment reads. One 512-thread block per CU,
// zero main-loop barriers: each wave streams 16-row A tiles via a prefetched
// register double-buffer.
// MODE 0: A = Abf rows. Epi: OutB = bf16(z + bias).
// MODE 1: A row e = [x[tgt[e]] | Aux[e]] (KTOT=512).
//         Epi: g = sigmoid(z+bias); OutB = bf16(tx + hew*g*m).
// MODE 2: A row r = Idx[r]>=0 ? Aux[Idx[r]] : x[r].
//         Epi: OutF = clip(z+bias, 0, 1) fp32.
template<int MODE, int KTOT, int NCOLS, bool XB>
__global__ __launch_bounds__(512, 2) void wgemm(
    const ushort_t* __restrict__ Abf,
    const float* __restrict__ Xf,
    const ushort_t* __restrict__ Xb,
    const ushort_t* __restrict__ Aux,
    const int* __restrict__ Idx,
    const float* __restrict__ Hew,
    const ushort_t* __restrict__ Wt,     // [256][KTOT] bf16 (pre-transposed)
    const float* __restrict__ Bias,
    ushort_t* __restrict__ OutB,
    float* __restrict__ OutF,
    int M)
{
    constexpr int KS  = KTOT / 32;       // K-steps (MFMA K=32 each)
    constexpr int CT  = NCOLS / 16;      // output col-tiles
    constexpr int CPR = KTOT / 8;        // 16B chunks per W row
    const int c0 = blockIdx.y * NCOLS;
    const int tid = threadIdx.x;
    const int wv = tid >> 6;
    const int lane = tid & 63;

    __shared__ __align__(16) ushort_t Ws[NCOLS * KTOT];   // 128 KiB

    // ---- stage W: pre-swizzled global source, linear LDS dest (rule #21) ----
    {
        constexpr int TOT = NCOLS * CPR;                  // 8192 chunks
        for (int base = wv * 64; base < TOT; base += 512) {
            int id = base + lane;                          // wave-uniform base + lane
            int n = id / CPR, cs = id % CPR;
            int cg = cs ^ (n & 7);                         // involution
            glds16(Wt + (size_t)(c0 + n) * KTOT + cg * 8, (char*)Ws + (size_t)id * 16);
        }
    }
    __syncthreads();   // drains vmcnt; the only barrier in the kernel

    float biasv[CT];
#pragma unroll
    for (int t = 0; t < CT; ++t) biasv[t] = Bias[c0 + t * 16 + (lane & 15)];

    const int ntiles = (M + 15) >> 4;
    const int stride = gridDim.x * 8;
    int tile = blockIdx.x * 8 + wv;
    if (tile >= ntiles) return;

    const int arow = lane & 15;     // A-fragment row within 16-row tile
    const int kg = lane >> 4;       // k-group (8 elements)

    auto loadA = [&](int tl, short8* A) {
        int r = tl * 16 + arow; if (r > M - 1) r = M - 1;
        if constexpr (MODE == 0) {
            const ushort_t* p = Abf + (size_t)r * KTOT + kg * 8;
#pragma unroll
            for (int kk = 0; kk < KS; ++kk) A[kk] = *(const short8*)(p + kk * 32);
        } else if constexpr (MODE == 1) {
            int tr = Idx[r];
            if constexpr (XB) {
                const ushort_t* p = Xb + (size_t)tr * 256 + kg * 8;
#pragma unroll
                for (int kk = 0; kk < 8; ++kk) A[kk] = *(const short8*)(p + kk * 32);
            } else {
                const float* p = Xf + (size_t)tr * 256 + kg * 8;
#pragma unroll
                for (int kk = 0; kk < 8; ++kk) { int4v d = pack_f32x8_bf16(p + kk * 32); A[kk] = *(short8*)&d; }
            }
            const ushort_t* q = Aux + (size_t)r * 256 + kg * 8;
#pragma unroll
            for (int kk = 0; kk < 8; ++kk) A[8 + kk] = *(const short8*)(q + kk * 32);
        } else {
            int e = Idx[r];
            if constexpr (XB) {
                const ushort_t* p = (e >= 0) ? (Aux + (size_t)e * 256) : (Xb + (size_t)r * 256);
                p += kg * 8;
#pragma unroll
                for (int kk = 0; kk < KS; ++kk) A[kk] = *(const short8*)(p + kk * 32);
            } else {
                if (e >= 0) {
                    const ushort_t* p = Aux + (size_t)e * 256 + kg * 8;
#pragma unroll
                    for (int kk = 0; kk < KS; ++kk) A[kk] = *(const short8*)(p + kk * 32);
                } else {
                    const float* p = Xf + (size_t)r * 256 + kg * 8;
#pragma unroll
                    for (int kk = 0; kk < KS; ++kk) { int4v d = pack_f32x8_bf16(p + kk * 32); A[kk] = *(short8*)&d; }
                }
            }
        }
    };

    auto computeEpi = [&](int tl, const short8* A) {
        f32x4 acc[CT];
#pragma unroll
        for (int t = 0; t < CT; ++t) acc[t] = (f32x4){0.f, 0.f, 0.f, 0.f};
#pragma unroll
        for (int kk = 0; kk < KS; ++kk) {
            short8 a = A[kk];
            int cs = (kg + 4 * kk) ^ (lane & 7);           // n&7 == lane&7 since n = arow+16t
#pragma unroll
            for (int t = 0; t < CT; ++t) {
                int n = arow + 16 * t;
                short8 b = *(const short8*)((const char*)Ws + ((size_t)n * CPR + cs) * 16);
                acc[t] = __builtin_amdgcn_mfma_f32_16x16x32_bf16(a, b, acc[t], 0, 0, 0);
            }
        }
        // epilogue; C/D layout: col = lane&15 (+16t), row = (lane>>4)*4 + i
        int rbase = tl * 16 + (lane >> 4) * 4;
        if constexpr (MODE == 0) {
#pragma unroll
            for (int t = 0; t < CT; ++t) {
                int col = c0 + t * 16 + (lane & 15);
#pragma unroll
                for (int i = 0; i < 4; ++i) {
                    int rg = rbase + i;
                    if (rg < M) OutB[(size_t)rg * 256 + col] = f2bf(acc[t][i] + biasv[t]);
                }
            }
        } else if constexpr (MODE == 1) {
            int4v tg4; f32x4 hw4;
            if (rbase + 3 < M) {
                tg4 = *(const int4v*)(Idx + rbase);
                hw4 = *(const f32x4*)(Hew + rbase);
            } else {
#pragma unroll
                for (int i = 0; i < 4; ++i) {
                    int rg = rbase + i < M ? rbase + i : M - 1;
                    tg4[i] = Idx[rg]; hw4[i] = Hew[rg];
                }
            }
#pragma unroll
            for (int t = 0; t < CT; ++t) {
                int col = c0 + t * 16 + (lane & 15);
#pragma unroll
                for (int i = 0; i < 4; ++i) {
                    int rg = rbase + i;
                    if (rg < M) {
                        float z = acc[t][i] + biasv[t];
                        float g = 1.f / (1.f + __expf(-z));
                        float tx = XB ? bf2f(Xb[(size_t)tg4[i] * 256 + col])
                                      : Xf[(size_t)tg4[i] * 256 + col];
                        float m = bf2f(Aux[(size_t)rg * 256 + col]);
                        OutB[(size_t)rg * 256 + col] = f2bf(tx + hw4[i] * g * m);
                    }
                }
            }
        } else {
#pragma unroll
            for (int t = 0; t < CT; ++t) {
                int col = c0 + t * 16 + (lane & 15);
#pragma unroll
                for (int i = 0; i < 4; ++i) {
                    int rg = rbase + i;
                    if (rg < M) {
                        float z = acc[t][i] + biasv[t];
                        OutF[(size_t)rg * 256 + col] = fminf(fmaxf(z, 0.f), 1.f);
                    }
                }
            }
        }
    };

    short8 A0[KS], A1[KS];
    loadA(tile, A0);
    while (true) {
        int t1 = tile + stride;
        if (t1 < ntiles) loadA(t1, A1);     // prefetch overlaps compute below
        computeEpi(tile, A0);
        tile = t1;
        if (tile >= ntiles) break;
        int t2 = tile + stride;
        if (t2 < ntiles) loadA(t2, A0);
        computeEpi(tile, A1);
        tile = t2;
        if (tile >= ntiles) break;
    }
}

extern "C" void kernel_launch(void* const* d_in, const int* in_sizes, int n_in,
                              void* d_out, int out_size, void* d_ws, size_t ws_size,
                              hipStream_t stream) {
    const float* x      = (const float*)d_in[0];
    const int*   he_ptr = (const int*)d_in[1];
    const int*   he_src = (const int*)d_in[2];
    const int*   he_tgt = (const int*)d_in[3];
    const float* he_w   = (const float*)d_in[4];
    const float* W_msg  = (const float*)d_in[5];
    const float* b_msg  = (const float*)d_in[6];
    const float* W_gate = (const float*)d_in[7];
    const float* b_gate = (const float*)d_in[8];
    const float* W_upd  = (const float*)d_in[9];
    const float* b_upd  = (const float*)d_in[10];

    const int E = in_sizes[3];
    const int R = in_sizes[0] / H;

    const size_t wbytes = (size_t)(65536 + 131072 + 65536) * 2;
    const size_t needA = (size_t)R * H * 2 + (size_t)E * H * 2 * 2 + (size_t)R * 4 + wbytes;
    const bool bigws = ws_size >= needA;

    if (bigws) {
        char* ws = (char*)d_ws;
        ushort_t* yb   = (ushort_t*)ws;                                // R*256 bf16(x)
        ushort_t* buf0 = yb + (size_t)R * H;                           // E*256: smb, later updb
        ushort_t* buf1 = buf0 + (size_t)E * H;                         // E*256: msgb
        int*      imap = (int*)(buf1 + (size_t)E * H);                 // R
        ushort_t* Wmt  = (ushort_t*)((char*)imap + (size_t)R * 4);
        ushort_t* Wgt  = Wmt + 256 * 256;
        ushort_t* Wut  = Wgt + 256 * 512;

        prep_weights<<<512, 256, 0, stream>>>(W_msg, W_gate, W_upd, Wmt, Wgt, Wut);
        imap_init<<<(R + 255) / 256, 256, 0, stream>>>(imap, R);
        imap_scatter<<<(E + 255) / 256, 256, 0, stream>>>(he_tgt, imap, E);
        conv_bf16<<<2048, 256, 0, stream>>>(x, yb, (size_t)R * H / 8);
        seg_mean_bf16<<<(E + 3) / 4, 256, 0, stream>>>(yb, he_ptr, he_src, buf0, E);

        wgemm<0, 256, 256, true><<<dim3(256, 1), 512, 0, stream>>>(
            buf0, nullptr, yb, nullptr, nullptr, nullptr, Wmt, b_msg, buf1, nullptr, E);
        wgemm<1, 512, 128, true><<<dim3(256, 2), 512, 0, stream>>>(
            nullptr, nullptr, yb, buf1, he_tgt, he_w, Wgt, b_gate, buf0, nullptr, E);
        wgemm<2, 256, 256, true><<<dim3(256, 1), 512, 0, stream>>>(
            nullptr, nullptr, yb, buf0, imap, nullptr, Wut, b_upd, nullptr, (float*)d_out, R);
    } else {
        char* ws = (char*)d_ws;
        ushort_t* buf0 = (ushort_t*)ws;
        ushort_t* buf1 = buf0 + (size_t)E * H;
        int*      imap = (int*)(buf1 + (size_t)E * H);
        ushort_t* Wmt  = (ushort_t*)((char*)imap + (size_t)R * 4);
        ushort_t* Wgt  = Wmt + 256 * 256;
        ushort_t* Wut  = Wgt + 256 * 512;

        prep_weights<<<512, 256, 0, stream>>>(W_msg, W_gate, W_upd, Wmt, Wgt, Wut);
        imap_init<<<(R + 255) / 256, 256, 0, stream>>>(imap, R);
        imap_scatter<<<(E + 255) / 256, 256, 0, stream>>>(he_tgt, imap, E);
        seg_mean_f32w<<<(E + 3) / 4, 256, 0, stream>>>(x, he_ptr, he_src, buf0, E);

        wgemm<0, 256, 256, false><<<dim3(256, 1), 512, 0, stream>>>(
            buf0, nullptr, nullptr, nullptr, nullptr, nullptr, Wmt, b_msg, buf1, nullptr, E);
        wgemm<1, 512, 128, false><<<dim3(256, 2), 512, 0, stream>>>(
            nullptr, x, nullptr, buf1, he_tgt, he_w, Wgt, b_gate, buf0, nullptr, E);
        wgemm<2, 256, 256, false><<<dim3(256, 1), 512, 0, stream>>>(
            nullptr, x, nullptr, buf0, imap, nullptr, Wut, b_upd, nullptr, (float*)d_out, R);
    }
}